// Round 12
// baseline (586.524 us; speedup 1.0000x reference)
//
#include <hip/hip_runtime.h>
#include <math.h>

#define N_USERS 50000
#define N_ITEMS 50000
#define N_NODES 100000
#define NNZ_E   1600000
#define EMB     64
#define BATCH   4096
#define REG_C   1e-5f

// bucketed geometry
#define BSH    8                                  // 256 rows per bucket
#define NBUCK  ((N_NODES + 255) >> BSH)           // 391
#define BCAP   5120                               // mean 4096 + 16 sigma slack
#define NSB    256                                // binning blocks
#define CHUNK  ((NNZ_E + NSB - 1) / NSB)          // 6250 edges per block

// loss reduction geometry
#define LNB    256                                // partial blocks
#define LSPB   (BATCH / LNB)                      // 16 samples per block

__device__ __forceinline__ unsigned short f2bf(float f) {
    unsigned u = __float_as_uint(f);
    u = (u + 0x7FFFu + ((u >> 16) & 1u)) >> 16;   // round-to-nearest-even
    return (unsigned short)u;
}
__device__ __forceinline__ float bf2f(unsigned short h) {
    return __uint_as_float(((unsigned)h) << 16);
}

// ---------------------------------------------------------------------------
// ego16 = bf16(concat(user_emb, item_emb))
// ---------------------------------------------------------------------------
__global__ __launch_bounds__(256) void init_ego(const float* __restrict__ ue,
                                                const float* __restrict__ ie,
                                                unsigned short* __restrict__ ego16) {
    const int total = N_NODES * EMB / 4;      // float4 count
    const int uf4   = N_USERS * EMB / 4;
    for (int idx = blockIdx.x * blockDim.x + threadIdx.x; idx < total;
         idx += gridDim.x * blockDim.x) {
        float4 v = (idx < uf4) ? ((const float4*)ue)[idx]
                               : ((const float4*)ie)[idx - uf4];
        ushort4 h;
        h.x = f2bf(v.x); h.y = f2bf(v.y); h.z = f2bf(v.z); h.w = f2bf(v.w);
        *(ushort4*)&ego16[(size_t)idx * 4] = h;
    }
}

// ---------------------------------------------------------------------------
// Pass 1: bin edges by 256-row bucket.
// bin entry: ( (row&255)<<17 | col , val_bits )
// ---------------------------------------------------------------------------
__global__ __launch_bounds__(256) void binscatter(const int* __restrict__ rw,
                                                  const int* __restrict__ cl,
                                                  const float* __restrict__ val,
                                                  int* __restrict__ bcnt,
                                                  int2* __restrict__ bin) {
    __shared__ int lcount[NBUCK];
    __shared__ int lbase[NBUCK];
    const int t    = threadIdx.x;
    const int eend = min(NNZ_E, (int)((blockIdx.x + 1) * CHUNK));

    for (int b = t; b < NBUCK; b += 256) lcount[b] = 0;
    __syncthreads();

    for (int e = blockIdx.x * CHUNK + t; e < eend; e += 256)
        atomicAdd(&lcount[rw[e] >> BSH], 1);
    __syncthreads();

    for (int b = t; b < NBUCK; b += 256) {
        const int c = lcount[b];
        lbase[b]  = (c > 0) ? atomicAdd(&bcnt[b], c) : 0;
        lcount[b] = 0;
    }
    __syncthreads();

    for (int e = blockIdx.x * CHUNK + t; e < eend; e += 256) {
        const int r = rw[e];
        const int b = r >> BSH;
        const int ofs = atomicAdd(&lcount[b], 1);
        const int rel = lbase[b] + ofs;
        if (rel < BCAP)
            bin[(size_t)b * BCAP + rel] =
                make_int2(((r & 255) << 17) | cl[e], __float_as_int(val[e]));
    }
}

// ---------------------------------------------------------------------------
// Pass 2 (merged): per bucket — compute own base from bcnt, col-sort order
// in LDS, per-row scan, write row_ptr + exact CSR (col-sorted within rows).
// ---------------------------------------------------------------------------
__global__ __launch_bounds__(256) void sort_place(const int* __restrict__ bcnt,
                                                  const int2* __restrict__ bin,
                                                  int* __restrict__ row_ptr,
                                                  int2* __restrict__ ep) {
    __shared__ int2 ebuf[BCAP];                 // 40 KB
    __shared__ unsigned short sidx[BCAP];       // 10 KB
    __shared__ int cnt[256];
    __shared__ int rcnt[256];
    __shared__ int rbase[256];
    __shared__ int wt[4];
    __shared__ int sbase;
    const int t    = threadIdx.x;
    const int buck = blockIdx.x;
    const int lane = t & 63, w = t >> 6;
    const int n    = min(bcnt[buck], BCAP);

    // bucket base = sum of clamped counts of preceding buckets
    int ps = 0;
    for (int j = t; j < buck; j += 256) ps += min(bcnt[j], BCAP);
    #pragma unroll
    for (int m = 32; m; m >>= 1) ps += __shfl_xor(ps, m);
    if (lane == 0) wt[w] = ps;
    cnt[t]  = 0;
    rcnt[t] = 0;
    __syncthreads();                            // S1
    if (t == 0) sbase = wt[0] + wt[1] + wt[2] + wt[3];
    for (int i = t; i < n; i += 256) ebuf[i] = bin[(size_t)buck * BCAP + i];
    __syncthreads();                            // S2: ebuf + sbase ready

    // colkey histogram (key 0..195)
    for (int i = t; i < n; i += 256)
        atomicAdd(&cnt[(ebuf[i].x & 0x1FFFF) >> 9], 1);
    __syncthreads();                            // S3

    // exclusive scan of cnt -> cursor
    {
        const int c = cnt[t];
        int incl = c;
        #pragma unroll
        for (int off = 1; off < 64; off <<= 1) {
            const int v = __shfl_up(incl, off);
            if (lane >= off) incl += v;
        }
        if (lane == 63) wt[w] = incl;
        __syncthreads();                        // S4
        int wb = 0;
        #pragma unroll
        for (int q = 0; q < 4; ++q) wb += (q < w) ? wt[q] : 0;
        cnt[t] = wb + incl - c;
    }
    __syncthreads();                            // S5

    // build sorted order + row histogram
    for (int i = t; i < n; i += 256) {
        const int pos = atomicAdd(&cnt[(ebuf[i].x & 0x1FFFF) >> 9], 1);
        sidx[pos] = (unsigned short)i;
    }
    for (int i = t; i < n; i += 256)
        atomicAdd(&rcnt[ebuf[i].x >> 17], 1);
    __syncthreads();                            // S6

    // exclusive scan of rcnt -> global row bases + row_ptr
    {
        const int c2 = rcnt[t];
        int incl = c2;
        #pragma unroll
        for (int off = 1; off < 64; off <<= 1) {
            const int v = __shfl_up(incl, off);
            if (lane >= off) incl += v;
        }
        if (lane == 63) wt[w] = incl;
        __syncthreads();                        // S7
        int wb = 0;
        #pragma unroll
        for (int q = 0; q < 4; ++q) wb += (q < w) ? wt[q] : 0;
        const int myb = sbase + wb + incl - c2;
        rbase[t] = myb;
        const int gr = (buck << BSH) + t;
        if (gr < N_NODES) row_ptr[gr] = myb;
        if (buck == NBUCK - 1 && t == 0) row_ptr[N_NODES] = sbase + n;
        rcnt[t] = 0;                            // becomes cursor
    }
    __syncthreads();                            // S8

    // place edges at exact CSR positions, iterating in col-sorted order
    for (int k = t; k < n; k += 256) {
        const int2 e  = ebuf[sidx[k]];
        const int r8  = e.x >> 17;
        const int ofs = atomicAdd(&rcnt[r8], 1);
        ep[rbase[r8] + ofs] = make_int2(e.x & 0x1FFFF, e.y);
    }
}

// ---------------------------------------------------------------------------
// Fused SpMM + layer update. Per 64-row block:
//   phase 1: 8 waves x 8 rows gather-accumulate side in registers (edge-pair
//            form), write HT/GT tiles directly to LDS as bf16 (side never
//            touches global memory);
//   phase 2: tile GEMM + bias + leaky-relu, write new ego (ping-pong buffer).
// LDS = 16 KB bf16 tiles + 32 KB f32 weights = 48 KB -> 3 blocks/CU.
// ---------------------------------------------------------------------------
__global__ __launch_bounds__(512) void spmm_layer(const int* __restrict__ rp,
                                                  const int2* __restrict__ ep,
                                                  const unsigned short* __restrict__ xin,
                                                  unsigned short* __restrict__ xout,
                                                  const float* __restrict__ Wgc,
                                                  const float* __restrict__ bgc,
                                                  const float* __restrict__ Wbi,
                                                  const float* __restrict__ bbi) {
    __shared__ unsigned short HT[EMB * EMB];   // [dim][row^sw]  bf16  8 KB
    __shared__ unsigned short GT[EMB * EMB];   // [dim][row^sw]  bf16  8 KB
    __shared__ float WG[EMB * EMB];            // 16 KB
    __shared__ float WB[EMB * EMB];            // 16 KB

    const int t  = threadIdx.x;
    const int r0 = blockIdx.x * 64;

    // stage weights (1024 float4 over 512 threads)
    #pragma unroll
    for (int it = 0; it < 2; ++it) {
        const int f4 = t + it * 512;
        const int d  = f4 >> 4, c0 = (f4 & 15) * 4;
        *(float4*)&WG[d * EMB + c0] = ((const float4*)Wgc)[f4];
        *(float4*)&WB[d * EMB + c0] = ((const float4*)Wbi)[f4];
    }

    // phase 1: gather
    const int w = t >> 6, l = t & 63, sub = l & 31, half = l >> 5;
    #pragma unroll 1
    for (int q = 0; q < 8; ++q) {
        const int rl = w * 8 + q;
        const int r  = r0 + rl;
        float a0 = 0.f, a1 = 0.f;
        if (r < N_NODES) {
            const int beg = rp[r], end = rp[r + 1];
            int e = beg;
            for (; e + 8 <= end; e += 8) {
                int2 p[4];
                #pragma unroll
                for (int z = 0; z < 4; ++z) p[z] = ep[e + 2 * z + half];
                unsigned xv[4];
                #pragma unroll
                for (int z = 0; z < 4; ++z)
                    xv[z] = *(const unsigned*)&xin[((size_t)p[z].x << 6) + (sub << 1)];
                #pragma unroll
                for (int z = 0; z < 4; ++z) {
                    const float v = __int_as_float(p[z].y);
                    a0 += v * __uint_as_float(xv[z] << 16);
                    a1 += v * __uint_as_float(xv[z] & 0xFFFF0000u);
                }
            }
            for (; e + 2 <= end; e += 2) {
                const int2 pq = ep[e + half];
                const unsigned xv = *(const unsigned*)&xin[((size_t)pq.x << 6) + (sub << 1)];
                const float v = __int_as_float(pq.y);
                a0 += v * __uint_as_float(xv << 16);
                a1 += v * __uint_as_float(xv & 0xFFFF0000u);
            }
            if (e < end) {                     // odd tail: only half==0 counts
                const int2 pq = ep[e];
                const unsigned xv = *(const unsigned*)&xin[((size_t)pq.x << 6) + (sub << 1)];
                const float v = half ? 0.f : __int_as_float(pq.y);
                a0 += v * __uint_as_float(xv << 16);
                a1 += v * __uint_as_float(xv & 0xFFFF0000u);
            }
        }
        a0 += __shfl_xor(a0, 32);
        a1 += __shfl_xor(a1, 32);
        // every lane now holds both sums; lane covers dim dd = 2*sub + half
        const int dd = (sub << 1) + half;
        const float h = half ? a1 : a0;
        float ev = 0.f;
        if (r < N_NODES) ev = bf2f(xin[((size_t)r << 6) + dd]);
        const float g  = ev * (h - ev);
        const int sw = (dd & 7) << 2;
        HT[dd * EMB + (rl ^ sw)] = f2bf(h);
        GT[dd * EMB + (rl ^ sw)] = f2bf(g);
    }
    __syncthreads();

    // phase 2: GEMM. tr = rows 4tr..4tr+3, to = cols 2to,2to+1
    const int tr = t >> 5;
    const int to = t & 31;
    float acc[4][2];
    #pragma unroll
    for (int i2 = 0; i2 < 4; ++i2) { acc[i2][0] = 0.f; acc[i2][1] = 0.f; }

    #pragma unroll 8
    for (int d = 0; d < EMB; ++d) {
        const int sw = (d & 7) << 2;
        const ushort4 ah4 = *(const ushort4*)&HT[d * EMB + ((tr * 4) ^ sw)];
        const ushort4 ag4 = *(const ushort4*)&GT[d * EMB + ((tr * 4) ^ sw)];
        const float2 wg2 = *(const float2*)&WG[d * EMB + to * 2];
        const float2 wb2 = *(const float2*)&WB[d * EMB + to * 2];
        const float ah[4] = {bf2f(ah4.x), bf2f(ah4.y), bf2f(ah4.z), bf2f(ah4.w)};
        const float ag[4] = {bf2f(ag4.x), bf2f(ag4.y), bf2f(ag4.z), bf2f(ag4.w)};
        #pragma unroll
        for (int i2 = 0; i2 < 4; ++i2) {
            acc[i2][0] += ah[i2] * wg2.x + ag[i2] * wb2.x;
            acc[i2][1] += ah[i2] * wg2.y + ag[i2] * wb2.y;
        }
    }

    const float2 bg2 = *(const float2*)&bgc[to * 2];
    const float2 bb2 = *(const float2*)&bbi[to * 2];
    const float bs0 = bg2.x + bb2.x;
    const float bs1 = bg2.y + bb2.y;

    #pragma unroll
    for (int i2 = 0; i2 < 4; ++i2) {
        const int gr = r0 + tr * 4 + i2;
        if (gr < N_NODES) {
            float v0 = acc[i2][0] + bs0;
            float v1 = acc[i2][1] + bs1;
            v0 = (v0 >= 0.f) ? v0 : 0.01f * v0;
            v1 = (v1 >= 0.f) ? v1 : 0.01f * v1;
            const unsigned outp = (unsigned)f2bf(v0) | ((unsigned)f2bf(v1) << 16);
            ((unsigned*)xout)[(size_t)gr * 32 + to] = outp;
        }
    }
}

// ---------------------------------------------------------------------------
// gather + per-row L2 normalize for the 3*BATCH needed rows of this layer
// ---------------------------------------------------------------------------
__global__ __launch_bounds__(256) void gather_norm(const unsigned short* __restrict__ ego16,
                                                   const int* __restrict__ u,
                                                   const int* __restrict__ ii,
                                                   const int* __restrict__ jj,
                                                   float* __restrict__ Gk) {
    const int gtid = blockIdx.x * blockDim.x + threadIdx.x;
    const int wave = gtid >> 6;
    const int lane = threadIdx.x & 63;
    if (wave >= 3 * BATCH) return;
    const int a = wave / BATCH;
    const int b = wave - a * BATCH;
    const int node = (a == 0) ? u[b] : N_USERS + ((a == 1) ? ii[b] : jj[b]);
    const float v = bf2f(ego16[(size_t)node * EMB + lane]);
    float ss = v * v;
    #pragma unroll
    for (int m = 32; m; m >>= 1) ss += __shfl_xor(ss, m);
    const float inv = 1.f / fmaxf(sqrtf(ss), 1e-12f);
    Gk[(size_t)wave * EMB + lane] = v * inv;
}

// ---------------------------------------------------------------------------
// BPR loss + L2 reg: stage 1 — per-block partials (no global atomics)
// ---------------------------------------------------------------------------
__global__ __launch_bounds__(256) void loss_partial(const float* __restrict__ ue,
                                                    const float* __restrict__ ie,
                                                    const float* __restrict__ G,
                                                    const int* __restrict__ u,
                                                    const int* __restrict__ ii,
                                                    const int* __restrict__ jj,
                                                    float* __restrict__ partial) {
    __shared__ float wsum[4];
    const int t    = threadIdx.x;
    const int lane = t & 63;
    const int w    = t >> 6;                 // wave 0..3

    float sum = 0.f;                          // wave-uniform accumulator
    #pragma unroll
    for (int s = 0; s < LSPB / 4; ++s) {
        const int b = blockIdx.x * LSPB + w * (LSPB / 4) + s;
        const int uu = u[b], pi = ii[b], nj = jj[b];
        float uv[4], pv[4], nv[4];
        uv[0] = ue[(size_t)uu * EMB + lane];
        pv[0] = ie[(size_t)pi * EMB + lane];
        nv[0] = ie[(size_t)nj * EMB + lane];
        #pragma unroll
        for (int k = 0; k < 3; ++k) {
            uv[k + 1] = G[(((size_t)k * 3 + 0) * BATCH + b) * EMB + lane];
            pv[k + 1] = G[(((size_t)k * 3 + 1) * BATCH + b) * EMB + lane];
            nv[k + 1] = G[(((size_t)k * 3 + 2) * BATCH + b) * EMB + lane];
        }
        float yui = 0.f, yuj = 0.f, l2 = 0.f;
        #pragma unroll
        for (int q = 0; q < 4; ++q) {
            yui += uv[q] * pv[q];
            yuj += uv[q] * nv[q];
            l2  += uv[q] * uv[q] + pv[q] * pv[q] + nv[q] * nv[q];
        }
        #pragma unroll
        for (int m = 32; m; m >>= 1) {
            yui += __shfl_xor(yui, m);
            yuj += __shfl_xor(yuj, m);
            l2  += __shfl_xor(l2, m);
        }
        const float d  = yui - yuj;
        const float sp = (d > 0.f) ? log1pf(expf(-d)) : (-d + log1pf(expf(d)));
        sum += sp * (1.f / BATCH) + REG_C * (l2 * 0.5f) * (1.f / BATCH);
    }
    if (lane == 0) wsum[w] = sum;
    __syncthreads();
    if (t == 0) partial[blockIdx.x] = wsum[0] + wsum[1] + wsum[2] + wsum[3];
}

// ---------------------------------------------------------------------------
// stage 2 — one block sums the 256 partials, writes out[0]
// ---------------------------------------------------------------------------
__global__ __launch_bounds__(256) void final_reduce(const float* __restrict__ partial,
                                                    float* __restrict__ out) {
    __shared__ float wsum[4];
    const int t = threadIdx.x;
    const int lane = t & 63, w = t >> 6;
    float v = partial[t];
    #pragma unroll
    for (int m = 32; m; m >>= 1) v += __shfl_xor(v, m);
    if (lane == 0) wsum[w] = v;
    __syncthreads();
    if (t == 0) out[0] = wsum[0] + wsum[1] + wsum[2] + wsum[3];
}

// ---------------------------------------------------------------------------
extern "C" void kernel_launch(void* const* d_in, const int* in_sizes, int n_in,
                              void* d_out, int out_size, void* d_ws, size_t ws_size,
                              hipStream_t stream) {
    const float* ue   = (const float*)d_in[0];
    const float* ie   = (const float*)d_in[1];
    const float* Wgc  = (const float*)d_in[2];
    const float* bgc  = (const float*)d_in[3];
    const float* Wbi  = (const float*)d_in[4];
    const float* bbi  = (const float*)d_in[5];
    const float* aval = (const float*)d_in[6];
    const int*   arow = (const int*)d_in[7];
    const int*   acol = (const int*)d_in[8];
    const int*   u    = (const int*)d_in[9];
    const int*   ii   = (const int*)d_in[10];
    const int*   jj   = (const int*)d_in[11];
    float* out = (float*)d_out;

    const size_t NE = (size_t)N_NODES * EMB;            // 6.4M elements
    char* p = (char*)d_ws;
    unsigned short* bufA = (unsigned short*)p;  p += NE * 2;                  // 12.8 MB
    unsigned short* bufB = (unsigned short*)p;  p += NE * 2;                  // 12.8 MB
    float* G     = (float*)p;                 p += (size_t)9 * BATCH * EMB * 4; // 9.4 MB
    float* lpart = (float*)p;                 p += (size_t)LNB * 4;
    int* row_ptr = (int*)p;                   p += (size_t)(N_NODES + 2) * 4;
    int* bcnt    = (int*)p;                   p += (size_t)(NBUCK + 1) * 4;
    p = (char*)(((uintptr_t)p + 15) & ~(uintptr_t)15);
    int2* epack  = (int2*)p;                  p += (size_t)NNZ_E * 8;           // 12.8 MB
    int2* bin    = (int2*)p;                  p += (size_t)NBUCK * BCAP * 8;    // 16.0 MB

    // ---- build bucketed, col-sorted CSR once -----------------------------
    hipMemsetAsync(bcnt, 0, (NBUCK + 1) * sizeof(int), stream);
    hipLaunchKernelGGL(binscatter, dim3(NSB), dim3(256), 0, stream,
                       arow, acol, aval, bcnt, bin);
    hipLaunchKernelGGL(sort_place, dim3(NBUCK), dim3(256), 0, stream,
                       bcnt, bin, row_ptr, epack);

    hipLaunchKernelGGL(init_ego, dim3(2048), dim3(256), 0, stream, ue, ie, bufA);

    const unsigned short* inb[3]  = {bufA, bufB, bufA};
    unsigned short*       outb[3] = {bufB, bufA, bufB};
    for (int k = 0; k < 3; ++k) {
        hipLaunchKernelGGL(spmm_layer, dim3((N_NODES + 63) / 64), dim3(512), 0, stream,
                           row_ptr, epack, inb[k], outb[k],
                           Wgc + (size_t)k * EMB * EMB, bgc + (size_t)k * EMB,
                           Wbi + (size_t)k * EMB * EMB, bbi + (size_t)k * EMB);
        hipLaunchKernelGGL(gather_norm, dim3((3 * BATCH + 3) / 4), dim3(256), 0, stream,
                           outb[k], u, ii, jj, G + (size_t)k * 3 * BATCH * EMB);
    }

    hipLaunchKernelGGL(loss_partial, dim3(LNB), dim3(256), 0, stream,
                       ue, ie, G, u, ii, jj, lpart);
    hipLaunchKernelGGL(final_reduce, dim3(1), dim3(256), 0, stream, lpart, out);
}